// Round 8
// baseline (181.453 us; speedup 1.0000x reference)
//
#include <hip/hip_runtime.h>
#include <hip/hip_bf16.h>

namespace {
constexpr int NB = 128;   // batch
constexpr int NL = 2048;  // seq len
constexpr int ND = 128;   // emb dim
constexpr int NH = 256;   // hidden
constexpr int NO = 128;   // encoder out dim
constexpr int NK = 64;    // top-k
constexpr int MCAP = 192; // candidate cap per batch
constexpr int HTHR = 96;  // histogram cumulative threshold
constexpr int BLOOP = 8;  // batches per score block
constexpr float MASK_FILL_F = -1e9f;
constexpr float LN_EPS_F = 1e-5f;
}

typedef __attribute__((ext_vector_type(8))) short bf16x8;
typedef __attribute__((ext_vector_type(4))) float f32x4;

__device__ __forceinline__ unsigned short bf16rne(float x) {
  unsigned u = __float_as_uint(x);
  return (unsigned short)((u + 0x7FFFu + ((u >> 16) & 1u)) >> 16);
}

// ---------- fused prep: W1 seq-slab -> bf16T | P (16-row blocks) | T (16-row) ----------
// grid: [0,ND) w1aT transpose; [ND, ND+NL/16) P; [ND+NL/16, +NB/16) T
__global__ __launch_bounds__(256) void k_prep(
    const float* __restrict__ W1, const float* __restrict__ pos,
    const float* __restrict__ tgt, const float* __restrict__ b1,
    unsigned short* __restrict__ W1aT, float* __restrict__ P,
    float* __restrict__ T) {
  const int blk = blockIdx.x, t = threadIdx.x;
  if (blk < ND) {  // W1aT[h][d]: d = blk, h = t
    W1aT[(size_t)t * ND + blk] = bf16rne(W1[(size_t)blk * NH + t]);
    return;
  }
  int r0, w_off, add_bias;
  const float* src;
  float* out;
  if (blk < ND + NL / 16) {
    r0 = (blk - ND) * 16; src = pos; out = P; w_off = ND; add_bias = 1;
  } else {
    r0 = (blk - ND - NL / 16) * 16; src = tgt; out = T; w_off = 2 * ND; add_bias = 0;
  }
  __shared__ float srow[16 * ND];  // 8 KB
  for (int i = t; i < 16 * ND; i += 256)
    srow[i] = src[(size_t)(r0 + (i >> 7)) * ND + (i & 127)];
  __syncthreads();
  const int h = t;
  const float binit = add_bias ? b1[h] : 0.0f;
  float acc[16];
#pragma unroll
  for (int i = 0; i < 16; ++i) acc[i] = binit;
  for (int d = 0; d < ND; ++d) {
    const float wv = W1[(size_t)(w_off + d) * NH + h];
#pragma unroll
    for (int i = 0; i < 16; ++i) acc[i] = fmaf(srow[i * ND + d], wv, acc[i]);
  }
#pragma unroll
  for (int i = 0; i < 16; ++i) out[(size_t)(r0 + i) * NH + h] = acc[i];
}

// ---------- approximate scores (pos-part dropped; 12-sigma-safe) ----------
// grid (16 l-tiles, 16 b-groups); 512 thr = 8 waves in 4h x 2l grid;
// wave (wh,wl) owns h in [wh*64,+64), l in [wl*64,+64).
// A = W1aT (seq slab, K=128) persistent in registers; seq tile dbuf in LDS.
__global__ __launch_bounds__(512, 2) void k_scores_mfma(
    const float* __restrict__ seq, const int* __restrict__ mask,
    const unsigned short* __restrict__ W1aT, const float* __restrict__ w2,
    const float* __restrict__ b2, const float* __restrict__ b1,
    const float* __restrict__ T, float* __restrict__ scores) {
  const int l0 = blockIdx.x * 128;
  const int b0 = blockIdx.y * BLOOP;
  const int t = threadIdx.x;
  const int lane = t & 63;
  const int w = t >> 6;      // 0..7
  const int wh = w & 3;      // h-block
  const int wl = w >> 2;     // l-block
  const int lh = lane & 15;
  const int kq = lane >> 4;  // 0..3

  __shared__ unsigned short sSeq[2][128 * 128];  // 2 x 32 KB dbuf, swizzled
  __shared__ float sRed[4][128];

  // resident A fragments: h = wh*64 + mt*16 + lh, k = ks*32 + kq*8
  bf16x8 a[4][4];
#pragma unroll
  for (int ks = 0; ks < 4; ++ks)
#pragma unroll
    for (int mt = 0; mt < 4; ++mt)
      a[ks][mt] = *(const bf16x8*)(
          W1aT + (size_t)(wh * 64 + mt * 16 + lh) * ND + ks * 32 + kq * 8);

  // epilogue constants: h = wh*64 + mt*16 + kq*4 + j  (C/D row mapping)
  float4 wv[4], b1v[4];
#pragma unroll
  for (int mt = 0; mt < 4; ++mt) {
    wv[mt] = *(const float4*)(w2 + wh * 64 + mt * 16 + kq * 4);
    b1v[mt] = *(const float4*)(b1 + wh * 64 + mt * 16 + kq * 4);
  }
  const float b2v = b2[0];

  ushort4 pf[8];
  auto prefetch = [&](int bb) {
    const float4* g = (const float4*)(seq + ((size_t)bb * NL + l0) * ND);
#pragma unroll
    for (int i = 0; i < 8; ++i) {
      const float4 f = g[t + i * 512];
      pf[i].x = bf16rne(f.x); pf[i].y = bf16rne(f.y);
      pf[i].z = bf16rne(f.z); pf[i].w = bf16rne(f.w);
    }
  };
  auto commit = [&](unsigned short* dst) {
#pragma unroll
    for (int i = 0; i < 8; ++i) {
      const int v = t + i * 512;        // ushort4 slot; 32 per 256B row
      const int row = v >> 5;
      const int c8 = (v & 31) * 8;
      const int off = (row << 8) + (c8 ^ ((row & 15) << 4));
      *(ushort4*)((char*)dst + off) = pf[i];
    }
  };

  prefetch(b0);
  commit((unsigned short*)sSeq[0]);
  __syncthreads();

#pragma unroll 1
  for (int j = 0; j < BLOOP; ++j) {
    const int b = b0 + j;
    unsigned short* cSeq = (unsigned short*)sSeq[j & 1];
    unsigned short* nSeq = (unsigned short*)sSeq[(j & 1) ^ 1];

    if (j + 1 < BLOOP) prefetch(b + 1);  // in flight across MFMA phase

    float4 Tv[4];
#pragma unroll
    for (int mt = 0; mt < 4; ++mt)
      Tv[mt] = *(const float4*)(T + (size_t)b * NH + wh * 64 + mt * 16 + kq * 4);

    f32x4 acc[4][4];  // [mt][nt]
#pragma unroll
    for (int mt = 0; mt < 4; ++mt)
#pragma unroll
      for (int nt = 0; nt < 4; ++nt) acc[mt][nt] = (f32x4){0.f, 0.f, 0.f, 0.f};

#pragma unroll
    for (int ks = 0; ks < 4; ++ks) {
      bf16x8 Bf[4];
#pragma unroll
      for (int nt = 0; nt < 4; ++nt) {
        const int row = wl * 64 + nt * 16 + lh;
        const int off = (row << 8) + (((ks << 6) + (kq << 4)) ^ ((row & 15) << 4));
        Bf[nt] = *(const bf16x8*)((const char*)cSeq + off);
      }
#pragma unroll
      for (int mt = 0; mt < 4; ++mt)
#pragma unroll
        for (int nt = 0; nt < 4; ++nt)
          acc[mt][nt] = __builtin_amdgcn_mfma_f32_16x16x32_bf16(
              a[ks][mt], Bf[nt], acc[mt][nt], 0, 0, 0);
    }
    __syncthreads();  // all waves done reading cSeq
    if (j + 1 < BLOOP) commit(nSeq);

    // epilogue: relu(z + T + b1) . w2, reduce over h
    float p[4] = {0.f, 0.f, 0.f, 0.f};
#pragma unroll
    for (int mt = 0; mt < 4; ++mt) {
#pragma unroll
      for (int nt = 0; nt < 4; ++nt) {
        float z;
        z = acc[mt][nt][0] + Tv[mt].x + b1v[mt].x; p[nt] = fmaf(fmaxf(z, 0.f), wv[mt].x, p[nt]);
        z = acc[mt][nt][1] + Tv[mt].y + b1v[mt].y; p[nt] = fmaf(fmaxf(z, 0.f), wv[mt].y, p[nt]);
        z = acc[mt][nt][2] + Tv[mt].z + b1v[mt].z; p[nt] = fmaf(fmaxf(z, 0.f), wv[mt].z, p[nt]);
        z = acc[mt][nt][3] + Tv[mt].w + b1v[mt].w; p[nt] = fmaf(fmaxf(z, 0.f), wv[mt].w, p[nt]);
      }
    }
#pragma unroll
    for (int nt = 0; nt < 4; ++nt) {
      float v = p[nt];
      v += __shfl_xor(v, 16);
      v += __shfl_xor(v, 32);
      if (lane < 16) sRed[wh][wl * 64 + nt * 16 + lane] = v;
    }
    __syncthreads();  // commit + sRed visible
    if (t < 128) {
      const int l = l0 + t;
      float sc = sRed[0][t] + sRed[1][t] + sRed[2][t] + sRed[3][t] + b2v;
      if (mask[(size_t)b * NL + l] == 0) sc = MASK_FILL_F;
      scores[(size_t)b * NL + l] = sc;
    }
  }
}

// ---------- per-batch candidate selection via 12-bit key histogram ----------
__global__ __launch_bounds__(512) void k_topM(
    const float* __restrict__ scores, int* __restrict__ cand_idx,
    int* __restrict__ cand_n) {
  const int b = blockIdx.x, t = threadIdx.x;
  __shared__ unsigned hist[4096];
  __shared__ unsigned chunk[512];
  __shared__ int sB;
  __shared__ unsigned sCntHi, sCntB;
  for (int i = t; i < 4096; i += 512) hist[i] = 0;
  if (t == 0) { sCntHi = 0; sCntB = 0; }
  __syncthreads();
  unsigned key[4];
#pragma unroll
  for (int i = 0; i < 4; ++i) {
    unsigned u = __float_as_uint(scores[(size_t)b * NL + t + i * 512]);
    u = (u & 0x80000000u) ? ~u : (u | 0x80000000u);
    key[i] = u;
    atomicAdd(&hist[u >> 20], 1u);
  }
  __syncthreads();
  {
    unsigned s = 0;
#pragma unroll
    for (int j = 0; j < 8; ++j) s += hist[t * 8 + j];
    chunk[t] = s;
  }
  __syncthreads();
  if (t == 0) {
    unsigned cum = 0;
    int c = 511;
    for (; c > 0; --c) {
      if (cum + chunk[c] >= (unsigned)HTHR) break;
      cum += chunk[c];
    }
    int bin = c * 8 + 7;
    for (; bin > c * 8; --bin) {
      if (cum + hist[bin] >= (unsigned)HTHR) break;
      cum += hist[bin];
    }
    sB = bin;
  }
  __syncthreads();
  const unsigned B = (unsigned)sB;
#pragma unroll
  for (int i = 0; i < 4; ++i) {
    if ((key[i] >> 20) > B) {
      unsigned pos = atomicAdd(&sCntHi, 1u);
      cand_idx[(size_t)b * MCAP + pos] = t + i * 512;
    }
  }
  __syncthreads();
  const unsigned hi = sCntHi;
#pragma unroll
  for (int i = 0; i < 4; ++i) {
    if ((key[i] >> 20) == B) {
      unsigned pos = atomicAdd(&sCntB, 1u);
      if (hi + pos < (unsigned)MCAP)
        cand_idx[(size_t)b * MCAP + hi + pos] = t + i * 512;
    }
  }
  __syncthreads();
  if (t == 0) {
    unsigned n = hi + sCntB;
    cand_n[b] = (int)(n < (unsigned)MCAP ? n : (unsigned)MCAP);
  }
}

// ---------- exact fp32 rescore of candidates ----------
__global__ __launch_bounds__(256) void k_rescore(
    const float* __restrict__ seq, const int* __restrict__ mask,
    const float* __restrict__ W1, const float* __restrict__ w2,
    const float* __restrict__ b2, const float* __restrict__ P,
    const float* __restrict__ T, const int* __restrict__ cand_idx,
    const int* __restrict__ cand_n, float* __restrict__ cscore) {
  const int b = blockIdx.y;
  const int s0 = blockIdx.x * 32;
  const int n = cand_n[b];
  if (s0 >= n) return;
  const int t = threadIdx.x;
  __shared__ float s_seq[32 * 128];
  __shared__ int s_l[32];
  if (t < 32) {
    const int slot = s0 + t;
    s_l[t] = (slot < n) ? cand_idx[(size_t)b * MCAP + slot] : 0;
  }
  __syncthreads();
#pragma unroll
  for (int i = 0; i < 4; ++i) {
    const int v = t + i * 256;
    const int r = v >> 5, c = v & 31;
    ((float4*)s_seq)[r * 32 + c] =
        ((const float4*)(seq + ((size_t)b * NL + s_l[r]) * ND))[c];
  }
  __syncthreads();

  const int hg = t & 63, rg = t >> 6;
  float acc[8][4];
#pragma unroll
  for (int r = 0; r < 8; ++r)
#pragma unroll
    for (int j = 0; j < 4; ++j) acc[r][j] = 0.0f;

  const float4* Wp = (const float4*)W1;
  for (int d0 = 0; d0 < ND; d0 += 4) {
    float4 wq[4];
#pragma unroll
    for (int j = 0; j < 4; ++j) wq[j] = Wp[(size_t)(d0 + j) * (NH / 4) + hg];
#pragma unroll
    for (int r = 0; r < 8; ++r) {
      const float4 s = *(const float4*)&s_seq[(rg * 8 + r) * ND + d0];
      const float sv[4] = {s.x, s.y, s.z, s.w};
#pragma unroll
      for (int j = 0; j < 4; ++j) {
        acc[r][0] = fmaf(sv[j], wq[j].x, acc[r][0]);
        acc[r][1] = fmaf(sv[j], wq[j].y, acc[r][1]);
        acc[r][2] = fmaf(sv[j], wq[j].z, acc[r][2]);
        acc[r][3] = fmaf(sv[j], wq[j].w, acc[r][3]);
      }
    }
  }

  const float4 wv = ((const float4*)w2)[hg];
  const float4 Tv = ((const float4*)(T + (size_t)b * NH))[hg];
  const float b2v = b2[0];
#pragma unroll
  for (int r = 0; r < 8; ++r) {
    const int l = s_l[rg * 8 + r];
    const float4 Pv = ((const float4*)(P + (size_t)l * NH))[hg];
    float z, p = 0.0f;
    z = acc[r][0] + Pv.x + Tv.x; p = fmaf(fmaxf(z, 0.0f), wv.x, p);
    z = acc[r][1] + Pv.y + Tv.y; p = fmaf(fmaxf(z, 0.0f), wv.y, p);
    z = acc[r][2] + Pv.z + Tv.z; p = fmaf(fmaxf(z, 0.0f), wv.z, p);
    z = acc[r][3] + Pv.w + Tv.w; p = fmaf(fmaxf(z, 0.0f), wv.w, p);
#pragma unroll
    for (int off = 32; off >= 1; off >>= 1) p += __shfl_xor(p, off);
    if (hg == 0) {
      float sc = p + b2v;
      if (mask[(size_t)b * NL + l] == 0) sc = MASK_FILL_F;
      cscore[(size_t)b * MCAP + s0 + rg * 8 + r] = sc;
    }
  }
}

// ---------- parallel rank-based top-64 + index-sort + softmax ----------
__global__ __launch_bounds__(256) void k_select(
    const float* __restrict__ cscore, const int* __restrict__ cand_idx,
    const int* __restrict__ cand_n, int* __restrict__ idx_sorted,
    float* __restrict__ attn) {
  const int b = blockIdx.x, t = threadIdx.x;
  __shared__ unsigned long long key[MCAP];
  __shared__ float val[MCAP];
  __shared__ int sel_l[NK];
  __shared__ float sel_v[NK];
  __shared__ int srt_l[NK];
  __shared__ float srt_v[NK];
  const int n = cand_n[b];
  for (int s = t; s < MCAP; s += 256) {
    unsigned long long kk = 0ull;
    float f = 0.0f;
    if (s < n) {
      f = cscore[(size_t)b * MCAP + s];
      unsigned u = __float_as_uint(f);
      u = (u & 0x80000000u) ? ~u : (u | 0x80000000u);
      const int l = cand_idx[(size_t)b * MCAP + s];
      kk = ((unsigned long long)u << 11) | (unsigned long long)(NL - 1 - l);
    }
    key[s] = kk;
    val[s] = f;
  }
  __syncthreads();

  for (int s = t; s < MCAP; s += 256) {
    if (s < n) {
      const unsigned long long mk = key[s];
      int rank = 0;
      for (int j = 0; j < n; ++j) rank += (key[j] > mk) ? 1 : 0;
      if (rank < NK) {
        sel_l[rank] = (NL - 1) - (int)(mk & 0x7FFull);
        sel_v[rank] = val[s];
      }
    }
  }
  __syncthreads();

  if (t < NK) {
    const int myl = sel_l[t];
    int pos = 0;
#pragma unroll 8
    for (int j = 0; j < NK; ++j) pos += (sel_l[j] < myl) ? 1 : 0;
    srt_l[pos] = myl;
    srt_v[pos] = sel_v[t];
  }
  __syncthreads();

  if (t < 64) {
    const float sc = srt_v[t];
    float m = sc;
#pragma unroll
    for (int off = 32; off >= 1; off >>= 1) m = fmaxf(m, __shfl_xor(m, off));
    const float e = expf(sc - m);
    float s = e;
#pragma unroll
    for (int off = 32; off >= 1; off >>= 1) s += __shfl_xor(s, off);
    attn[(size_t)b * NK + t] = e / s;
    idx_sorted[(size_t)b * NK + t] = srt_l[t];
  }
}

// ---------- encoder layer 1 ----------
__global__ __launch_bounds__(256) void k_enc1(
    const float* __restrict__ seq, const float* __restrict__ pos,
    const int* __restrict__ idx_sorted, const float* __restrict__ We1,
    const float* __restrict__ be1, float* __restrict__ h1) {
  const int qb = blockIdx.x;
  const int b = blockIdx.y;
  const int t = threadIdx.x;
  __shared__ float s_sel[16 * 256];
  __shared__ int s_idx[16];
  if (t < 16) s_idx[t] = idx_sorted[(size_t)b * NK + qb * 16 + t];
  __syncthreads();
  {
    const int k = t >> 4, q = t & 15;
    const int idx = s_idx[k];
    const float4* sr = (const float4*)(seq + ((size_t)b * NL + idx) * ND);
    const float4* pr = (const float4*)(pos + (size_t)idx * ND);
    float4* d1 = (float4*)&s_sel[k * 256];
    float4* d2 = (float4*)&s_sel[k * 256 + ND];
#pragma unroll
    for (int i = 0; i < 2; ++i) {
      d1[q + i * 16] = sr[q + i * 16];
      d2[q + i * 16] = pr[q + i * 16];
    }
  }
  __syncthreads();

  const int hg = t & 63, rg = t >> 6;
  float acc[4][4];
#pragma unroll
  for (int r = 0; r < 4; ++r)
#pragma unroll
    for (int j = 0; j < 4; ++j) acc[r][j] = 0.0f;

  const float4* Wp = (const float4*)We1;
  for (int d = 0; d < 2 * ND; ++d) {
    const float4 w = Wp[(size_t)d * (NH / 4) + hg];
#pragma unroll
    for (int r = 0; r < 4; ++r) {
      const float s = s_sel[(rg * 4 + r) * 256 + d];
      acc[r][0] = fmaf(s, w.x, acc[r][0]);
      acc[r][1] = fmaf(s, w.y, acc[r][1]);
      acc[r][2] = fmaf(s, w.z, acc[r][2]);
      acc[r][3] = fmaf(s, w.w, acc[r][3]);
    }
  }
  const float4 bev = ((const float4*)be1)[hg];
#pragma unroll
  for (int r = 0; r < 4; ++r) {
    float4 o;
    o.x = fmaxf(acc[r][0] + bev.x, 0.0f);
    o.y = fmaxf(acc[r][1] + bev.y, 0.0f);
    o.z = fmaxf(acc[r][2] + bev.z, 0.0f);
    o.w = fmaxf(acc[r][3] + bev.w, 0.0f);
    ((float4*)(h1 + ((size_t)b * NK + qb * 16 + rg * 4 + r) * NH))[hg] = o;
  }
}

// ---------- encoder layer 2 + attn pooling (k-split partials) ----------
__global__ __launch_bounds__(256) void k_enc2(
    const float* __restrict__ h1, const float* __restrict__ attn,
    const float* __restrict__ We2, const float* __restrict__ be2,
    float* __restrict__ part_g) {
  const int qb = blockIdx.x;  // k-range [qb*16, qb*16+16)
  const int b = blockIdx.y;
  const int t = threadIdx.x;
  __shared__ float s_h1[16 * NH];  // 16 KB
  {
    const float4* src = (const float4*)(h1 + ((size_t)b * NK + qb * 16) * NH);
    float4* dst = (float4*)s_h1;
#pragma unroll
    for (int i = 0; i < 4; ++i) dst[t + i * 256] = src[t + i * 256];
  }
  __syncthreads();

  const int og = t & 31;  // o = og*4+j
  const int kg = t >> 5;  // rows k = kg*2 + r
  float acc[2][4];
#pragma unroll
  for (int r = 0; r < 2; ++r)
#pragma unroll
    for (int j = 0; j < 4; ++j) acc[r][j] = 0.0f;

  const float4* Wp = (const float4*)We2;
  for (int d = 0; d < NH; ++d) {
    const float4 w = Wp[(size_t)d * (NO / 4) + og];
#pragma unroll
    for (int r = 0; r < 2; ++r) {
      const float s = s_h1[(kg * 2 + r) * NH + d];
      acc[r][0] = fmaf(s, w.x, acc[r][0]);
      acc[r][1] = fmaf(s, w.y, acc[r][1]);
      acc[r][2] = fmaf(s, w.z, acc[r][2]);
      acc[r][3] = fmaf(s, w.w, acc[r][3]);
    }
  }

  const float4 bev = ((const float4*)be2)[og];
  float part[4] = {0.0f, 0.0f, 0.0f, 0.0f};
#pragma unroll
  for (int r = 0; r < 2; ++r) {
    const int k = qb * 16 + kg * 2 + r;
    const float a = attn[(size_t)b * NK + k];
    part[0] = fmaf(a, acc[r][0] + bev.x, part[0]);
    part[1] = fmaf(a, acc[r][1] + bev.y, part[1]);
    part[2] = fmaf(a, acc[r][2] + bev.z, part[2]);
    part[3] = fmaf(a, acc[r][3] + bev.w, part[3]);
  }
#pragma unroll
  for (int j = 0; j < 4; ++j) part[j] += __shfl_xor(part[j], 32);  // kg pairs

  __syncthreads();
  float* red = s_h1;  // reuse: [4 waves][128]
  const int w = t >> 6;
  if ((t & 63) < 32) {
    ((float4*)red)[w * 32 + og] = make_float4(part[0], part[1], part[2], part[3]);
  }
  __syncthreads();
  if (t < NO) {
    part_g[((size_t)qb * NB + b) * NO + t] =
        red[t] + red[NO + t] + red[2 * NO + t] + red[3 * NO + t];
  }
}

// ---------- sum partials + layernorm ----------
__global__ __launch_bounds__(128) void k_ln(
    const float* __restrict__ part_g, const float* __restrict__ gamma,
    const float* __restrict__ beta, float* __restrict__ out) {
  const int b = blockIdx.x, t = threadIdx.x;
  __shared__ float rr[4];
  const float pooled = part_g[((size_t)0 * NB + b) * NO + t] +
                       part_g[((size_t)1 * NB + b) * NO + t] +
                       part_g[((size_t)2 * NB + b) * NO + t] +
                       part_g[((size_t)3 * NB + b) * NO + t];
  float s1 = pooled, s2 = pooled * pooled;
#pragma unroll
  for (int off = 32; off >= 1; off >>= 1) {
    s1 += __shfl_xor(s1, off);
    s2 += __shfl_xor(s2, off);
  }
  if ((t & 63) == 0) { rr[(t >> 6) * 2] = s1; rr[(t >> 6) * 2 + 1] = s2; }
  __syncthreads();
  const float S1 = rr[0] + rr[2];
  const float S2 = rr[1] + rr[3];
  const float mu = S1 / NO;
  const float var = S2 / NO - mu * mu;
  const float rs = rsqrtf(var + LN_EPS_F);
  out[(size_t)b * NO + t] = (pooled - mu) * rs * gamma[t] + beta[t];
}

extern "C" void kernel_launch(void* const* d_in, const int* in_sizes, int n_in,
                              void* d_out, int out_size, void* d_ws, size_t ws_size,
                              hipStream_t stream) {
  (void)in_sizes; (void)n_in; (void)out_size; (void)ws_size;
  const float* seq = (const float*)d_in[0];
  const int* mask = (const int*)d_in[1];
  const float* tgt = (const float*)d_in[2];
  const float* pos = (const float*)d_in[3];
  const float* W1 = (const float*)d_in[4];
  const float* b1 = (const float*)d_in[5];
  const float* w2 = (const float*)d_in[6];
  const float* b2 = (const float*)d_in[7];
  const float* We1 = (const float*)d_in[8];
  const float* be1 = (const float*)d_in[9];
  const float* We2 = (const float*)d_in[10];
  const float* be2 = (const float*)d_in[11];
  const float* gam = (const float*)d_in[12];
  const float* bet = (const float*)d_in[13];
  float* out = (float*)d_out;

  float* P = (float*)d_ws;                            // NL*NH
  float* T = P + (size_t)NL * NH;                     // NB*NH
  float* scores = T + (size_t)NB * NH;                // NB*NL
  float* attn = scores + (size_t)NB * NL;             // NB*NK
  float* h1 = attn + (size_t)NB * NK;                 // NB*NK*NH
  int* idxs = (int*)(h1 + (size_t)NB * NK * NH);      // NB*NK
  // scratch aliased into h1 (dead before k_enc1 writes h1):
  unsigned short* w1aT = (unsigned short*)h1;               // NH*ND bf16 = 16384 f
  int* cand_idx = (int*)(h1 + 16384);                       // NB*MCAP
  int* cand_n = cand_idx + (size_t)NB * MCAP;               // NB
  float* cscore = (float*)(cand_n + NB);                    // NB*MCAP
  // part_g aliases scores (dead after k_topM): 4*NB*NO <= NB*NL
  float* part_g = scores;

  k_prep<<<ND + NL / 16 + NB / 16, 256, 0, stream>>>(W1, pos, tgt, b1, w1aT, P, T);
  k_scores_mfma<<<dim3(NL / 128, NB / BLOOP), 512, 0, stream>>>(
      seq, mask, w1aT, w2, b2, b1, T, scores);
  k_topM<<<NB, 512, 0, stream>>>(scores, cand_idx, cand_n);
  k_rescore<<<dim3(MCAP / 32, NB), 256, 0, stream>>>(seq, mask, W1, w2, b2, P, T,
                                                     cand_idx, cand_n, cscore);
  k_select<<<NB, 256, 0, stream>>>(cscore, cand_idx, cand_n, idxs, attn);
  k_enc1<<<dim3(NK / 16, NB), 256, 0, stream>>>(seq, pos, idxs, We1, be1, h1);
  k_enc2<<<dim3(4, NB), 256, 0, stream>>>(h1, attn, We2, be2, part_g);
  k_ln<<<NB, 128, 0, stream>>>(part_g, gam, bet, out);
}

// Round 9
// 144.838 us; speedup vs baseline: 1.2528x; 1.2528x over previous
//
#include <hip/hip_runtime.h>
#include <hip/hip_bf16.h>

namespace {
constexpr int NB = 128;   // batch
constexpr int NL = 2048;  // seq len
constexpr int ND = 128;   // emb dim
constexpr int NH = 256;   // hidden
constexpr int NO = 128;   // encoder out dim
constexpr int NK = 64;    // top-k
constexpr int MCAP = 192; // candidate cap per batch
constexpr int HTHR = 96;  // histogram cumulative threshold (>=96 collected)
constexpr int BLOOP = 8;  // batches per score block
constexpr float MASK_FILL_F = -1e9f;
constexpr float LN_EPS_F = 1e-5f;
}

typedef __attribute__((ext_vector_type(8))) short bf16x8;
typedef __attribute__((ext_vector_type(4))) float f32x4;

__device__ __forceinline__ unsigned short bf16rne(float x) {
  unsigned u = __float_as_uint(x);
  return (unsigned short)((u + 0x7FFFu + ((u >> 16) & 1u)) >> 16);
}

// ---------- fused prep: W1 seq-slab -> bf16T | P[l,h] | T[b,h] ----------
// flat grid: [0,128) w1aT, [128,128+NL) P, then NB blocks T
// NOTE (R8 lesson): single-row contrib blocks (2304 total) beat 16-row blocks
// (264 total) — the small-block version runs 8 blocks/CU so the redundant
// W1 L2 re-reads (268 MB @ 34.5 TB/s ~ 8us) are throughput-hidden, while the
// big-block version is 1 wave/SIMD latency-bound on its serial d-loop.
__global__ __launch_bounds__(256) void k_prep(
    const float* __restrict__ W1, const float* __restrict__ pos,
    const float* __restrict__ tgt, const float* __restrict__ b1,
    unsigned short* __restrict__ W1aT, float* __restrict__ P,
    float* __restrict__ T) {
  const int blk = blockIdx.x, t = threadIdx.x;
  if (blk < ND) {  // W1aT[h][d]: d = blk (0..127), h = t (0..255)
    W1aT[(size_t)t * ND + blk] = bf16rne(W1[(size_t)blk * NH + t]);
    return;
  }
  int r, w_off, add_bias;
  const float* src;
  float* out;
  if (blk < ND + NL) {
    r = blk - ND; src = pos; out = P; w_off = ND; add_bias = 1;
  } else {
    r = blk - (ND + NL); src = tgt; out = T; w_off = 2 * ND; add_bias = 0;
  }
  __shared__ float row[ND];
  if (t < ND) row[t] = src[(size_t)r * ND + t];
  __syncthreads();
  float acc = add_bias ? b1[t] : 0.0f;
#pragma unroll 8
  for (int d = 0; d < ND; ++d)
    acc = fmaf(row[d], W1[(size_t)(w_off + d) * NH + t], acc);
  out[(size_t)r * NH + t] = acc;
}

// ---------- approximate scores (pos-part dropped; 12-sigma-safe) ----------
// grid (16 l-tiles, 16 b-groups); 512 thr = 8 waves in 4h x 2l grid;
// wave (wh,wl) owns h in [wh*64,+64), l in [wl*64, +64).
// A = W1aT (seq slab, K=128) persistent in registers; seq tile dbuf in LDS.
__global__ __launch_bounds__(512, 2) void k_scores_mfma(
    const float* __restrict__ seq, const int* __restrict__ mask,
    const unsigned short* __restrict__ W1aT, const float* __restrict__ w2,
    const float* __restrict__ b2, const float* __restrict__ b1,
    const float* __restrict__ T, float* __restrict__ scores) {
  const int l0 = blockIdx.x * 128;
  const int b0 = blockIdx.y * BLOOP;
  const int t = threadIdx.x;
  const int lane = t & 63;
  const int w = t >> 6;      // 0..7
  const int wh = w & 3;      // h-block
  const int wl = w >> 2;     // l-block
  const int lh = lane & 15;
  const int kq = lane >> 4;  // 0..3

  __shared__ unsigned short sSeq[2][128 * 128];  // 2 x 32 KB dbuf, swizzled
  __shared__ float sRed[4][128];

  // resident A fragments: h = wh*64 + mt*16 + lh, k = ks*32 + kq*8
  bf16x8 a[4][4];
#pragma unroll
  for (int ks = 0; ks < 4; ++ks)
#pragma unroll
    for (int mt = 0; mt < 4; ++mt)
      a[ks][mt] = *(const bf16x8*)(
          W1aT + (size_t)(wh * 64 + mt * 16 + lh) * ND + ks * 32 + kq * 8);

  // epilogue constants: h = wh*64 + mt*16 + kq*4 + j  (C/D row mapping)
  float4 wv[4], b1v[4];
#pragma unroll
  for (int mt = 0; mt < 4; ++mt) {
    wv[mt] = *(const float4*)(w2 + wh * 64 + mt * 16 + kq * 4);
    b1v[mt] = *(const float4*)(b1 + wh * 64 + mt * 16 + kq * 4);
  }
  const float b2v = b2[0];

  ushort4 pf[8];
  auto prefetch = [&](int bb) {
    const float4* g = (const float4*)(seq + ((size_t)bb * NL + l0) * ND);
#pragma unroll
    for (int i = 0; i < 8; ++i) {
      const float4 f = g[t + i * 512];
      pf[i].x = bf16rne(f.x); pf[i].y = bf16rne(f.y);
      pf[i].z = bf16rne(f.z); pf[i].w = bf16rne(f.w);
    }
  };
  auto commit = [&](unsigned short* dst) {
#pragma unroll
    for (int i = 0; i < 8; ++i) {
      const int v = t + i * 512;        // ushort4 slot; 32 per 256B row
      const int row = v >> 5;
      const int c8 = (v & 31) * 8;
      const int off = (row << 8) + (c8 ^ ((row & 15) << 4));
      *(ushort4*)((char*)dst + off) = pf[i];
    }
  };

  prefetch(b0);
  commit((unsigned short*)sSeq[0]);
  __syncthreads();

#pragma unroll 1
  for (int j = 0; j < BLOOP; ++j) {
    const int b = b0 + j;
    unsigned short* cSeq = (unsigned short*)sSeq[j & 1];
    unsigned short* nSeq = (unsigned short*)sSeq[(j & 1) ^ 1];

    if (j + 1 < BLOOP) prefetch(b + 1);  // in flight across MFMA phase

    float4 Tv[4];
#pragma unroll
    for (int mt = 0; mt < 4; ++mt)
      Tv[mt] = *(const float4*)(T + (size_t)b * NH + wh * 64 + mt * 16 + kq * 4);

    f32x4 acc[4][4];  // [mt][nt]
#pragma unroll
    for (int mt = 0; mt < 4; ++mt)
#pragma unroll
      for (int nt = 0; nt < 4; ++nt) acc[mt][nt] = (f32x4){0.f, 0.f, 0.f, 0.f};

#pragma unroll
    for (int ks = 0; ks < 4; ++ks) {
      bf16x8 Bf[4];
#pragma unroll
      for (int nt = 0; nt < 4; ++nt) {
        const int row = wl * 64 + nt * 16 + lh;
        const int off = (row << 8) + (((ks << 6) + (kq << 4)) ^ ((row & 15) << 4));
        Bf[nt] = *(const bf16x8*)((const char*)cSeq + off);
      }
#pragma unroll
      for (int mt = 0; mt < 4; ++mt)
#pragma unroll
        for (int nt = 0; nt < 4; ++nt)
          acc[mt][nt] = __builtin_amdgcn_mfma_f32_16x16x32_bf16(
              a[ks][mt], Bf[nt], acc[mt][nt], 0, 0, 0);
    }
    __syncthreads();  // all waves done reading cSeq
    if (j + 1 < BLOOP) commit(nSeq);

    // epilogue: relu(z + T + b1) . w2, reduce over h
    float p[4] = {0.f, 0.f, 0.f, 0.f};
#pragma unroll
    for (int mt = 0; mt < 4; ++mt) {
#pragma unroll
      for (int nt = 0; nt < 4; ++nt) {
        float z;
        z = acc[mt][nt][0] + Tv[mt].x + b1v[mt].x; p[nt] = fmaf(fmaxf(z, 0.f), wv[mt].x, p[nt]);
        z = acc[mt][nt][1] + Tv[mt].y + b1v[mt].y; p[nt] = fmaf(fmaxf(z, 0.f), wv[mt].y, p[nt]);
        z = acc[mt][nt][2] + Tv[mt].z + b1v[mt].z; p[nt] = fmaf(fmaxf(z, 0.f), wv[mt].z, p[nt]);
        z = acc[mt][nt][3] + Tv[mt].w + b1v[mt].w; p[nt] = fmaf(fmaxf(z, 0.f), wv[mt].w, p[nt]);
      }
    }
#pragma unroll
    for (int nt = 0; nt < 4; ++nt) {
      float v = p[nt];
      v += __shfl_xor(v, 16);
      v += __shfl_xor(v, 32);
      if (lane < 16) sRed[wh][wl * 64 + nt * 16 + lane] = v;
    }
    __syncthreads();  // commit + sRed visible
    if (t < 128) {
      const int l = l0 + t;
      float sc = sRed[0][t] + sRed[1][t] + sRed[2][t] + sRed[3][t] + b2v;
      if (mask[(size_t)b * NL + l] == 0) sc = MASK_FILL_F;
      scores[(size_t)b * NL + l] = sc;
    }
  }
}

// ---------- per-batch candidate selection via 12-bit key histogram ----------
__global__ __launch_bounds__(256) void k_topM(
    const float* __restrict__ scores, int* __restrict__ cand_idx,
    int* __restrict__ cand_n) {
  const int b = blockIdx.x, t = threadIdx.x;
  __shared__ unsigned hist[4096];
  __shared__ unsigned chunk[256];
  __shared__ int sB;
  __shared__ unsigned sCntHi, sCntB;
  for (int i = t; i < 4096; i += 256) hist[i] = 0;
  if (t == 0) { sCntHi = 0; sCntB = 0; }
  __syncthreads();
  unsigned key[8];
#pragma unroll
  for (int i = 0; i < 8; ++i) {
    unsigned u = __float_as_uint(scores[(size_t)b * NL + t + i * 256]);
    u = (u & 0x80000000u) ? ~u : (u | 0x80000000u);
    key[i] = u;
    atomicAdd(&hist[u >> 20], 1u);
  }
  __syncthreads();
  {
    unsigned s = 0;
#pragma unroll 4
    for (int j = 0; j < 16; ++j) s += hist[t * 16 + j];
    chunk[t] = s;
  }
  __syncthreads();
  if (t == 0) {
    unsigned cum = 0;
    int c = 255;
    for (; c > 0; --c) {
      if (cum + chunk[c] >= (unsigned)HTHR) break;
      cum += chunk[c];
    }
    int bin = c * 16 + 15;
    for (; bin > c * 16; --bin) {
      if (cum + hist[bin] >= (unsigned)HTHR) break;
      cum += hist[bin];
    }
    sB = bin;
  }
  __syncthreads();
  const unsigned B = (unsigned)sB;
#pragma unroll
  for (int i = 0; i < 8; ++i) {
    if ((key[i] >> 20) > B) {
      unsigned pos = atomicAdd(&sCntHi, 1u);
      cand_idx[(size_t)b * MCAP + pos] = t + i * 256;
    }
  }
  __syncthreads();
  const unsigned hi = sCntHi;
#pragma unroll
  for (int i = 0; i < 8; ++i) {
    if ((key[i] >> 20) == B) {
      unsigned pos = atomicAdd(&sCntB, 1u);
      if (hi + pos < (unsigned)MCAP)
        cand_idx[(size_t)b * MCAP + hi + pos] = t + i * 256;
    }
  }
  __syncthreads();
  if (t == 0) {
    unsigned n = hi + sCntB;
    cand_n[b] = (int)(n < (unsigned)MCAP ? n : (unsigned)MCAP);
  }
}

// ---------- exact fp32 rescore of candidates ----------
__global__ __launch_bounds__(256) void k_rescore(
    const float* __restrict__ seq, const int* __restrict__ mask,
    const float* __restrict__ W1, const float* __restrict__ w2,
    const float* __restrict__ b2, const float* __restrict__ P,
    const float* __restrict__ T, const int* __restrict__ cand_idx,
    const int* __restrict__ cand_n, float* __restrict__ cscore) {
  const int b = blockIdx.y;
  const int s0 = blockIdx.x * 32;
  const int n = cand_n[b];
  if (s0 >= n) return;
  const int t = threadIdx.x;
  __shared__ float s_seq[32 * 128];
  __shared__ int s_l[32];
  if (t < 32) {
    const int slot = s0 + t;
    s_l[t] = (slot < n) ? cand_idx[(size_t)b * MCAP + slot] : 0;
  }
  __syncthreads();
#pragma unroll
  for (int i = 0; i < 4; ++i) {
    const int v = t + i * 256;
    const int r = v >> 5, c = v & 31;
    ((float4*)s_seq)[r * 32 + c] =
        ((const float4*)(seq + ((size_t)b * NL + s_l[r]) * ND))[c];
  }
  __syncthreads();

  const int hg = t & 63, rg = t >> 6;
  float acc[8][4];
#pragma unroll
  for (int r = 0; r < 8; ++r)
#pragma unroll
    for (int j = 0; j < 4; ++j) acc[r][j] = 0.0f;

  const float4* Wp = (const float4*)W1;
  for (int d0 = 0; d0 < ND; d0 += 4) {
    float4 wq[4];
#pragma unroll
    for (int j = 0; j < 4; ++j) wq[j] = Wp[(size_t)(d0 + j) * (NH / 4) + hg];
#pragma unroll
    for (int r = 0; r < 8; ++r) {
      const float4 s = *(const float4*)&s_seq[(rg * 8 + r) * ND + d0];
      const float sv[4] = {s.x, s.y, s.z, s.w};
#pragma unroll
      for (int j = 0; j < 4; ++j) {
        acc[r][0] = fmaf(sv[j], wq[j].x, acc[r][0]);
        acc[r][1] = fmaf(sv[j], wq[j].y, acc[r][1]);
        acc[r][2] = fmaf(sv[j], wq[j].z, acc[r][2]);
        acc[r][3] = fmaf(sv[j], wq[j].w, acc[r][3]);
      }
    }
  }

  const float4 wv = ((const float4*)w2)[hg];
  const float4 Tv = ((const float4*)(T + (size_t)b * NH))[hg];
  const float b2v = b2[0];
#pragma unroll
  for (int r = 0; r < 8; ++r) {
    const int l = s_l[rg * 8 + r];
    const float4 Pv = ((const float4*)(P + (size_t)l * NH))[hg];
    float z, p = 0.0f;
    z = acc[r][0] + Pv.x + Tv.x; p = fmaf(fmaxf(z, 0.0f), wv.x, p);
    z = acc[r][1] + Pv.y + Tv.y; p = fmaf(fmaxf(z, 0.0f), wv.y, p);
    z = acc[r][2] + Pv.z + Tv.z; p = fmaf(fmaxf(z, 0.0f), wv.z, p);
    z = acc[r][3] + Pv.w + Tv.w; p = fmaf(fmaxf(z, 0.0f), wv.w, p);
#pragma unroll
    for (int off = 32; off >= 1; off >>= 1) p += __shfl_xor(p, off);
    if (hg == 0) {
      float sc = p + b2v;
      if (mask[(size_t)b * NL + l] == 0) sc = MASK_FILL_F;
      cscore[(size_t)b * MCAP + s0 + rg * 8 + r] = sc;
    }
  }
}

// ---------- parallel rank-based top-64 + index-sort + softmax ----------
__global__ __launch_bounds__(256) void k_select(
    const float* __restrict__ cscore, const int* __restrict__ cand_idx,
    const int* __restrict__ cand_n, int* __restrict__ idx_sorted,
    float* __restrict__ attn) {
  const int b = blockIdx.x, t = threadIdx.x;
  __shared__ unsigned long long key[MCAP];
  __shared__ float val[MCAP];
  __shared__ int sel_l[NK];
  __shared__ float sel_v[NK];
  __shared__ int srt_l[NK];
  __shared__ float srt_v[NK];
  const int n = cand_n[b];
  for (int s = t; s < MCAP; s += 256) {
    unsigned long long kk = 0ull;
    float f = 0.0f;
    if (s < n) {
      f = cscore[(size_t)b * MCAP + s];
      unsigned u = __float_as_uint(f);
      u = (u & 0x80000000u) ? ~u : (u | 0x80000000u);
      const int l = cand_idx[(size_t)b * MCAP + s];
      kk = ((unsigned long long)u << 11) | (unsigned long long)(NL - 1 - l);
    }
    key[s] = kk;
    val[s] = f;
  }
  __syncthreads();

  for (int s = t; s < MCAP; s += 256) {
    if (s < n) {
      const unsigned long long mk = key[s];
      int rank = 0;
      for (int j = 0; j < n; ++j) rank += (key[j] > mk) ? 1 : 0;
      if (rank < NK) {
        sel_l[rank] = (NL - 1) - (int)(mk & 0x7FFull);
        sel_v[rank] = val[s];
      }
    }
  }
  __syncthreads();

  if (t < NK) {
    const int myl = sel_l[t];
    int pos = 0;
#pragma unroll 8
    for (int j = 0; j < NK; ++j) pos += (sel_l[j] < myl) ? 1 : 0;
    srt_l[pos] = myl;
    srt_v[pos] = sel_v[t];
  }
  __syncthreads();

  if (t < 64) {
    const float sc = srt_v[t];
    float m = sc;
#pragma unroll
    for (int off = 32; off >= 1; off >>= 1) m = fmaxf(m, __shfl_xor(m, off));
    const float e = expf(sc - m);
    float s = e;
#pragma unroll
    for (int off = 32; off >= 1; off >>= 1) s += __shfl_xor(s, off);
    attn[(size_t)b * NK + t] = e / s;
    idx_sorted[(size_t)b * NK + t] = srt_l[t];
  }
}

// ---------- encoder layer 1 ----------
__global__ __launch_bounds__(256) void k_enc1(
    const float* __restrict__ seq, const float* __restrict__ pos,
    const int* __restrict__ idx_sorted, const float* __restrict__ We1,
    const float* __restrict__ be1, float* __restrict__ h1) {
  const int qb = blockIdx.x;
  const int b = blockIdx.y;
  const int t = threadIdx.x;
  __shared__ float s_sel[16 * 256];
  __shared__ int s_idx[16];
  if (t < 16) s_idx[t] = idx_sorted[(size_t)b * NK + qb * 16 + t];
  __syncthreads();
  {
    const int k = t >> 4, q = t & 15;
    const int idx = s_idx[k];
    const float4* sr = (const float4*)(seq + ((size_t)b * NL + idx) * ND);
    const float4* pr = (const float4*)(pos + (size_t)idx * ND);
    float4* d1 = (float4*)&s_sel[k * 256];
    float4* d2 = (float4*)&s_sel[k * 256 + ND];
#pragma unroll
    for (int i = 0; i < 2; ++i) {
      d1[q + i * 16] = sr[q + i * 16];
      d2[q + i * 16] = pr[q + i * 16];
    }
  }
  __syncthreads();

  const int hg = t & 63, rg = t >> 6;
  float acc[4][4];
#pragma unroll
  for (int r = 0; r < 4; ++r)
#pragma unroll
    for (int j = 0; j < 4; ++j) acc[r][j] = 0.0f;

  const float4* Wp = (const float4*)We1;
  for (int d = 0; d < 2 * ND; ++d) {
    const float4 w = Wp[(size_t)d * (NH / 4) + hg];
#pragma unroll
    for (int r = 0; r < 4; ++r) {
      const float s = s_sel[(rg * 4 + r) * 256 + d];
      acc[r][0] = fmaf(s, w.x, acc[r][0]);
      acc[r][1] = fmaf(s, w.y, acc[r][1]);
      acc[r][2] = fmaf(s, w.z, acc[r][2]);
      acc[r][3] = fmaf(s, w.w, acc[r][3]);
    }
  }
  const float4 bev = ((const float4*)be1)[hg];
#pragma unroll
  for (int r = 0; r < 4; ++r) {
    float4 o;
    o.x = fmaxf(acc[r][0] + bev.x, 0.0f);
    o.y = fmaxf(acc[r][1] + bev.y, 0.0f);
    o.z = fmaxf(acc[r][2] + bev.z, 0.0f);
    o.w = fmaxf(acc[r][3] + bev.w, 0.0f);
    ((float4*)(h1 + ((size_t)b * NK + qb * 16 + rg * 4 + r) * NH))[hg] = o;
  }
}

// ---------- encoder layer 2 + attn pooling (k-split partials) ----------
__global__ __launch_bounds__(256) void k_enc2(
    const float* __restrict__ h1, const float* __restrict__ attn,
    const float* __restrict__ We2, const float* __restrict__ be2,
    float* __restrict__ part_g) {
  const int qb = blockIdx.x;  // k-range [qb*16, qb*16+16)
  const int b = blockIdx.y;
  const int t = threadIdx.x;
  __shared__ float s_h1[16 * NH];  // 16 KB
  {
    const float4* src = (const float4*)(h1 + ((size_t)b * NK + qb * 16) * NH);
    float4* dst = (float4*)s_h1;
#pragma unroll
    for (int i = 0; i < 4; ++i) dst[t + i * 256] = src[t + i * 256];
  }
  __syncthreads();

  const int og = t & 31;  // o = og*4+j
  const int kg = t >> 5;  // rows k = kg*2 + r
  float acc[2][4];
#pragma unroll
  for (int r = 0; r < 2; ++r)
#pragma unroll
    for (int j = 0; j < 4; ++j) acc[r][j] = 0.0f;

  const float4* Wp = (const float4*)We2;
  for (int d = 0; d < NH; ++d) {
    const float4 w = Wp[(size_t)d * (NO / 4) + og];
#pragma unroll
    for (int r = 0; r < 2; ++r) {
      const float s = s_h1[(kg * 2 + r) * NH + d];
      acc[r][0] = fmaf(s, w.x, acc[r][0]);
      acc[r][1] = fmaf(s, w.y, acc[r][1]);
      acc[r][2] = fmaf(s, w.z, acc[r][2]);
      acc[r][3] = fmaf(s, w.w, acc[r][3]);
    }
  }

  const float4 bev = ((const float4*)be2)[og];
  float part[4] = {0.0f, 0.0f, 0.0f, 0.0f};
#pragma unroll
  for (int r = 0; r < 2; ++r) {
    const int k = qb * 16 + kg * 2 + r;
    const float a = attn[(size_t)b * NK + k];
    part[0] = fmaf(a, acc[r][0] + bev.x, part[0]);
    part[1] = fmaf(a, acc[r][1] + bev.y, part[1]);
    part[2] = fmaf(a, acc[r][2] + bev.z, part[2]);
    part[3] = fmaf(a, acc[r][3] + bev.w, part[3]);
  }
#pragma unroll
  for (int j = 0; j < 4; ++j) part[j] += __shfl_xor(part[j], 32);  // kg pairs

  __syncthreads();
  float* red = s_h1;  // reuse: [4 waves][128]
  const int w = t >> 6;
  if ((t & 63) < 32) {
    ((float4*)red)[w * 32 + og] = make_float4(part[0], part[1], part[2], part[3]);
  }
  __syncthreads();
  if (t < NO) {
    part_g[((size_t)qb * NB + b) * NO + t] =
        red[t] + red[NO + t] + red[2 * NO + t] + red[3 * NO + t];
  }
}

// ---------- sum partials + layernorm ----------
__global__ __launch_bounds__(128) void k_ln(
    const float* __restrict__ part_g, const float* __restrict__ gamma,
    const float* __restrict__ beta, float* __restrict__ out) {
  const int b = blockIdx.x, t = threadIdx.x;
  __shared__ float rr[4];
  const float pooled = part_g[((size_t)0 * NB + b) * NO + t] +
                       part_g[((size_t)1 * NB + b) * NO + t] +
                       part_g[((size_t)2 * NB + b) * NO + t] +
                       part_g[((size_t)3 * NB + b) * NO + t];
  float s1 = pooled, s2 = pooled * pooled;
#pragma unroll
  for (int off = 32; off >= 1; off >>= 1) {
    s1 += __shfl_xor(s1, off);
    s2 += __shfl_xor(s2, off);
  }
  if ((t & 63) == 0) { rr[(t >> 6) * 2] = s1; rr[(t >> 6) * 2 + 1] = s2; }
  __syncthreads();
  const float S1 = rr[0] + rr[2];
  const float S2 = rr[1] + rr[3];
  const float mu = S1 / NO;
  const float var = S2 / NO - mu * mu;
  const float rs = rsqrtf(var + LN_EPS_F);
  out[(size_t)b * NO + t] = (pooled - mu) * rs * gamma[t] + beta[t];
}

extern "C" void kernel_launch(void* const* d_in, const int* in_sizes, int n_in,
                              void* d_out, int out_size, void* d_ws, size_t ws_size,
                              hipStream_t stream) {
  (void)in_sizes; (void)n_in; (void)out_size; (void)ws_size;
  const float* seq = (const float*)d_in[0];
  const int* mask = (const int*)d_in[1];
  const float* tgt = (const float*)d_in[2];
  const float* pos = (const float*)d_in[3];
  const float* W1 = (const float*)d_in[4];
  const float* b1 = (const float*)d_in[5];
  const float* w2 = (const float*)d_in[6];
  const float* b2 = (const float*)d_in[7];
  const float* We1 = (const float*)d_in[8];
  const float* be1 = (const float*)d_in[9];
  const float* We2 = (const float*)d_in[10];
  const float* be2 = (const float*)d_in[11];
  const float* gam = (const float*)d_in[12];
  const float* bet = (const float*)d_in[13];
  float* out = (float*)d_out;

  float* P = (float*)d_ws;                            // NL*NH
  float* T = P + (size_t)NL * NH;                     // NB*NH
  float* scores = T + (size_t)NB * NH;                // NB*NL
  float* attn = scores + (size_t)NB * NL;             // NB*NK
  float* h1 = attn + (size_t)NB * NK;                 // NB*NK*NH
  int* idxs = (int*)(h1 + (size_t)NB * NK * NH);      // NB*NK
  // scratch aliased into h1 (dead before k_enc1 writes h1):
  unsigned short* w1aT = (unsigned short*)h1;               // NH*ND bf16 = 16384 f
  int* cand_idx = (int*)(h1 + 16384);                       // NB*MCAP
  int* cand_n = cand_idx + (size_t)NB * MCAP;               // NB
  float* cscore = (float*)(cand_n + NB);                    // NB*MCAP
  // part_g aliases scores (dead after k_topM): 4*NB*NO <= NB*NL
  float* part_g = scores;

  k_prep<<<ND + NL + NB, 256, 0, stream>>>(W1, pos, tgt, b1, w1aT, P, T);
  k_scores_mfma<<<dim3(NL / 128, NB / BLOOP), 512, 0, stream>>>(
      seq, mask, w1aT, w2, b2, b1, T, scores);
  k_topM<<<NB, 256, 0, stream>>>(scores, cand_idx, cand_n);
  k_rescore<<<dim3(MCAP / 32, NB), 256, 0, stream>>>(seq, mask, W1, w2, b2, P, T,
                                                     cand_idx, cand_n, cscore);
  k_select<<<NB, 256, 0, stream>>>(cscore, cand_idx, cand_n, idxs, attn);
  k_enc1<<<dim3(NK / 16, NB), 256, 0, stream>>>(seq, pos, idxs, We1, be1, h1);
  k_enc2<<<dim3(4, NB), 256, 0, stream>>>(h1, attn, We2, be2, part_g);
  k_ln<<<NB, 128, 0, stream>>>(part_g, gam, bet, out);
}